// Round 3
// baseline (100.637 us; speedup 1.0000x reference)
//
#include <hip/hip_runtime.h>

// Problem constants (fixed by setup_inputs): B=4, T=28, N=1024, D=3
constexpr int Bc = 4;
constexpr int Tc = 28;
constexpr int Nc = 1024;
constexpr int Dc = 3;
constexpr int BT = Bc * Tc;       // 112
constexpr float OFFS = 512.0f;    // keeps surrogate v = ||t||^2+OFFS-2p.t positive-ish; ordering only

// ws layout (floats), ALL slots written unconditionally -> no memset needed:
//   partial[224]      : per-block weighted smooth-l1 sums
//   psum[224*3]       : per-block pred-coordinate sums (each block owns 512 preds)
//   tsum[112*3]       : per-bt target-coordinate sums (written by ph==0 block)
constexpr int WS_PARTIAL = 0;
constexpr int WS_PSUM    = 224;
constexpr int WS_TSUM    = 224 + 224 * 3;   // 896
// total 1232 floats

__device__ __forceinline__ float sl1(float d) {
    d = fabsf(d);
    return d < 1.0f ? 0.5f * d * d : d - 0.5f;
}

// Grid: 224 = 112 (b,t) x 2 pred-halves. Block: 256 threads, 2 preds/thread.
// All 1024 targets of the (b,t) staged in LDS as packed float4 [x,y,z,||t||^2+OFFS].
// Inner loop: 1 broadcast ds_read_b128 + 6 FMA + 6 cmp/sel for 2 pred evals.
// Surrogate v = tn' - 2 p.t is argmin-equivalent (per-pred monotone shift);
// strict < keeps the first minimum -> matches jnp.argmin tie-break.
__global__ __launch_bounds__(256) void chamfer_kernel(
    const float* __restrict__ X, const float* __restrict__ Tg,
    const float* __restrict__ W, float* __restrict__ ws)
{
    __shared__ float4 sT4[Nc];      // 16 KB packed targets
    __shared__ float sred[4][8];

    const int bt  = blockIdx.x >> 1;
    const int ph  = blockIdx.x & 1;
    const int tid = threadIdx.x;

    // ---- load this thread's 2 preds (overlaps with staging below) ----
    const float* xb = X + (size_t)bt * (Nc * Dc);
    const int n0 = ph * 512 + tid;
    const int n1 = n0 + 256;
    const float pAx = xb[n0 * 3 + 0], pAy = xb[n0 * 3 + 1], pAz = xb[n0 * 3 + 2];
    const float pBx = xb[n1 * 3 + 0], pBy = xb[n1 * 3 + 1], pBz = xb[n1 * 3 + 2];

    // ---- stage + pack 4 targets per thread; centroid target-sums ride along ----
    const float4* tg4 = (const float4*)(Tg + (size_t)bt * (Nc * Dc));
    const float4 r0 = tg4[3 * tid + 0];
    const float4 r1 = tg4[3 * tid + 1];
    const float4 r2 = tg4[3 * tid + 2];
    // targets 4t+0..3 = (r0.x,r0.y,r0.z) (r0.w,r1.x,r1.y) (r1.z,r1.w,r2.x) (r2.y,r2.z,r2.w)
    sT4[4 * tid + 0] = make_float4(r0.x, r0.y, r0.z, fmaf(r0.x, r0.x, fmaf(r0.y, r0.y, fmaf(r0.z, r0.z, OFFS))));
    sT4[4 * tid + 1] = make_float4(r0.w, r1.x, r1.y, fmaf(r0.w, r0.w, fmaf(r1.x, r1.x, fmaf(r1.y, r1.y, OFFS))));
    sT4[4 * tid + 2] = make_float4(r1.z, r1.w, r2.x, fmaf(r1.z, r1.z, fmaf(r1.w, r1.w, fmaf(r2.x, r2.x, OFFS))));
    sT4[4 * tid + 3] = make_float4(r2.y, r2.z, r2.w, fmaf(r2.y, r2.y, fmaf(r2.z, r2.z, fmaf(r2.w, r2.w, OFFS))));
    const float tsx = r0.x + r0.w + r1.z + r2.y;
    const float tsy = r0.y + r1.x + r1.w + r2.z;
    const float tsz = r0.z + r1.y + r2.x + r2.w;
    __syncthreads();

    const float cA0 = -2.0f * pAx, cA1 = -2.0f * pAy, cA2 = -2.0f * pAz;
    const float cB0 = -2.0f * pBx, cB1 = -2.0f * pBy, cB2 = -2.0f * pBz;

    float bestA = 3.4e38f, bestB = 3.4e38f;
    int iA = 0, iB = 0;
    #pragma unroll 4
    for (int m = 0; m < Nc; ++m) {
        const float4 t = sT4[m];  // broadcast b128: conflict-free, 1 LDS issue / 2 evals
        float vA = fmaf(cA0, t.x, fmaf(cA1, t.y, fmaf(cA2, t.z, t.w)));
        float vB = fmaf(cB0, t.x, fmaf(cB1, t.y, fmaf(cB2, t.z, t.w)));
        bool ca = vA < bestA; bestA = ca ? vA : bestA; iA = ca ? m : iA;  // strict <: first min
        bool cb = vB < bestB; bestB = cb ? vB : bestB; iB = cb ? m : iB;
    }

    // ---- epilogue: gather winners from LDS, smooth-L1 on true coordinates ----
    const float4 tA = sT4[iA];
    const float4 tB = sT4[iB];
    float s = sl1(pAx - tA.x) + sl1(pAy - tA.y) + sl1(pAz - tA.z)
            + sl1(pBx - tB.x) + sl1(pBy - tB.y) + sl1(pBz - tB.z);

    // ---- 7 block reductions batched through one syncthreads ----
    float vals[7] = { s, pAx + pBx, pAy + pBy, pAz + pBz, tsx, tsy, tsz };
    const int lane = tid & 63, wid = tid >> 6;
    #pragma unroll
    for (int k = 0; k < 7; ++k) {
        float v = vals[k];
        #pragma unroll
        for (int off = 32; off; off >>= 1) v += __shfl_down(v, off, 64);
        if (lane == 0) sred[wid][k] = v;
    }
    __syncthreads();
    if (tid == 0) {
        float tot[7];
        #pragma unroll
        for (int k = 0; k < 7; ++k)
            tot[k] = sred[0][k] + sred[1][k] + sred[2][k] + sred[3][k];
        ws[WS_PARTIAL + blockIdx.x] = tot[0] * W[bt];        // weighted sl1 sum
        ws[WS_PSUM + blockIdx.x * 3 + 0] = tot[1];
        ws[WS_PSUM + blockIdx.x * 3 + 1] = tot[2];
        ws[WS_PSUM + blockIdx.x * 3 + 2] = tot[3];
        if (ph == 0) {
            ws[WS_TSUM + bt * 3 + 0] = tot[4];
            ws[WS_TSUM + bt * 3 + 1] = tot[5];
            ws[WS_TSUM + bt * 3 + 2] = tot[6];
        }
    }
}

// One block: sum 224 weighted partials -> out[0]; centroid loss from sums -> out[1].
// Plain stores (no memset, no atomics). Reads K1's global writes (same-stream
// kernel ordering guarantees visibility).
__global__ __launch_bounds__(256) void finalize_kernel(
    const float* __restrict__ ws, float* __restrict__ out)
{
    __shared__ float sred[4][2];
    const int tid = threadIdx.x;

    float lp = (tid < 224) ? ws[WS_PARTIAL + tid] : 0.0f;

    float lc = 0.0f;
    if (tid < BT) {
        const float inv = 1.0f / Nc;
        #pragma unroll
        for (int c = 0; c < 3; ++c) {
            float pm = (ws[WS_PSUM + (2 * tid) * 3 + c] + ws[WS_PSUM + (2 * tid + 1) * 3 + c]) * inv;
            float tm = ws[WS_TSUM + tid * 3 + c] * inv;
            lc += sl1(pm - tm);
        }
    }

    const int lane = tid & 63, wid = tid >> 6;
    #pragma unroll
    for (int off = 32; off; off >>= 1) {
        lp += __shfl_down(lp, off, 64);
        lc += __shfl_down(lc, off, 64);
    }
    if (lane == 0) { sred[wid][0] = lp; sred[wid][1] = lc; }
    __syncthreads();
    if (tid == 0) {
        float tlp = sred[0][0] + sred[1][0] + sred[2][0] + sred[3][0];
        float tlc = sred[0][1] + sred[1][1] + sred[2][1] + sred[3][1];
        // loss = sum_bt w_bt * (sl1sum_bt / (N*D)) / B
        out[0] = tlp * (1.0f / (Nc * Dc)) * (1.0f / Bc);
        // lossc = sum over [B,T,3] / (B*3)
        out[1] = tlc * (1.0f / (Bc * Dc));
    }
}

extern "C" void kernel_launch(void* const* d_in, const int* in_sizes, int n_in,
                              void* d_out, int out_size, void* d_ws, size_t ws_size,
                              hipStream_t stream) {
    const float* X  = (const float*)d_in[0];  // X_v        [4,28,1024,3]
    const float* Tg = (const float*)d_in[1];  // target_X_v [4,28,1024,3]
    const float* W  = (const float*)d_in[2];  // weights    [4,28]
    float* out = (float*)d_out;               // {loss, lossc}
    float* ws  = (float*)d_ws;                // 1232 floats, all written before read

    chamfer_kernel<<<BT * 2, 256, 0, stream>>>(X, Tg, W, ws);
    finalize_kernel<<<1, 256, 0, stream>>>(ws, out);
}

// Round 4
// 88.609 us; speedup vs baseline: 1.1357x; 1.1357x over previous
//
#include <hip/hip_runtime.h>

// Problem constants (fixed by setup_inputs): B=4, T=28, N=1024, D=3
constexpr int Bc = 4;
constexpr int Tc = 28;
constexpr int Nc = 1024;
constexpr int Dc = 3;
constexpr int BT = Bc * Tc;       // 112
constexpr float OFFS = 512.0f;    // keeps surrogate v = ||t||^2+OFFS-2p.t positive; ordering only

// ws layout (floats), ALL slots written unconditionally -> no memset needed:
constexpr int WS_PARTIAL = 0;            // [224]   per-block weighted sl1 sums
constexpr int WS_PSUM    = 224;          // [224*3] per-block pred-coord sums
constexpr int WS_TSUM    = 224 + 224*3;  // [112*3] per-bt target-coord sums
// total 1232 floats

__device__ __forceinline__ float sl1(float d) {
    d = fabsf(d);
    return d < 1.0f ? 0.5f * d * d : d - 0.5f;
}

// Grid: 224 = 112 (b,t) x 2 pred-halves. Block: 256 threads, 2 preds/thread.
// All 1024 targets staged in LDS as packed float4 [x,y,z,||t||^2+OFFS].
// Inner loop is explicitly software-pipelined: two 8-target register stages;
// while stage A computes (~200 VALU cyc), stage B's 8 ds_read_b128 are in
// flight (~120 cyc latency) -> latency hidden even at 1 wave/SIMD.
// R3 post-mortem: without this, the loop ran latency-serialized at 111 cyc/iter.
__global__ __launch_bounds__(256) void chamfer_kernel(
    const float* __restrict__ X, const float* __restrict__ Tg,
    const float* __restrict__ W, float* __restrict__ ws)
{
    __shared__ float4 sT4[Nc];      // 16 KB packed targets
    __shared__ float sred[4][8];

    const int bt  = blockIdx.x >> 1;
    const int ph  = blockIdx.x & 1;
    const int tid = threadIdx.x;

    // ---- this thread's 2 preds ----
    const float* xb = X + (size_t)bt * (Nc * Dc);
    const int n0 = ph * 512 + tid;
    const int n1 = n0 + 256;
    const float pAx = xb[n0 * 3 + 0], pAy = xb[n0 * 3 + 1], pAz = xb[n0 * 3 + 2];
    const float pBx = xb[n1 * 3 + 0], pBy = xb[n1 * 3 + 1], pBz = xb[n1 * 3 + 2];

    // ---- stage + pack 4 targets per thread; centroid target-sums ride along ----
    const float4* tg4 = (const float4*)(Tg + (size_t)bt * (Nc * Dc));
    const float4 r0 = tg4[3 * tid + 0];
    const float4 r1 = tg4[3 * tid + 1];
    const float4 r2 = tg4[3 * tid + 2];
    sT4[4 * tid + 0] = make_float4(r0.x, r0.y, r0.z, fmaf(r0.x, r0.x, fmaf(r0.y, r0.y, fmaf(r0.z, r0.z, OFFS))));
    sT4[4 * tid + 1] = make_float4(r0.w, r1.x, r1.y, fmaf(r0.w, r0.w, fmaf(r1.x, r1.x, fmaf(r1.y, r1.y, OFFS))));
    sT4[4 * tid + 2] = make_float4(r1.z, r1.w, r2.x, fmaf(r1.z, r1.z, fmaf(r1.w, r1.w, fmaf(r2.x, r2.x, OFFS))));
    sT4[4 * tid + 3] = make_float4(r2.y, r2.z, r2.w, fmaf(r2.y, r2.y, fmaf(r2.z, r2.z, fmaf(r2.w, r2.w, OFFS))));
    const float tsx = r0.x + r0.w + r1.z + r2.y;
    const float tsy = r0.y + r1.x + r1.w + r2.z;
    const float tsz = r0.z + r1.y + r2.x + r2.w;
    __syncthreads();

    const float cA0 = -2.0f * pAx, cA1 = -2.0f * pAy, cA2 = -2.0f * pAz;
    const float cB0 = -2.0f * pBx, cB1 = -2.0f * pBy, cB2 = -2.0f * pBz;

    float bestA = 3.4e38f, bestB = 3.4e38f;
    int iA = 0, iB = 0;

    constexpr int PF = 8;           // targets per pipeline stage
    float4 bufA[PF], bufB[PF];

    #pragma unroll
    for (int j = 0; j < PF; ++j) bufA[j] = sT4[j];

    for (int m0 = 0; m0 < Nc; m0 += 2 * PF) {
        // issue stage-B loads, then compute on stage A (loads fly during compute)
        #pragma unroll
        for (int j = 0; j < PF; ++j) bufB[j] = sT4[m0 + PF + j];
        #pragma unroll
        for (int j = 0; j < PF; ++j) {
            const float4 t = bufA[j];
            const int m = m0 + j;
            float vA = fmaf(cA0, t.x, fmaf(cA1, t.y, fmaf(cA2, t.z, t.w)));
            float vB = fmaf(cB0, t.x, fmaf(cB1, t.y, fmaf(cB2, t.z, t.w)));
            bool ca = vA < bestA; bestA = ca ? vA : bestA; iA = ca ? m : iA;  // strict <: first min
            bool cb = vB < bestB; bestB = cb ? vB : bestB; iB = cb ? m : iB;
        }
        // issue next-iteration stage-A loads, then compute on stage B
        #pragma unroll
        for (int j = 0; j < PF; ++j) bufA[j] = sT4[(m0 + 2 * PF + j) & (Nc - 1)];
        #pragma unroll
        for (int j = 0; j < PF; ++j) {
            const float4 t = bufB[j];
            const int m = m0 + PF + j;
            float vA = fmaf(cA0, t.x, fmaf(cA1, t.y, fmaf(cA2, t.z, t.w)));
            float vB = fmaf(cB0, t.x, fmaf(cB1, t.y, fmaf(cB2, t.z, t.w)));
            bool ca = vA < bestA; bestA = ca ? vA : bestA; iA = ca ? m : iA;
            bool cb = vB < bestB; bestB = cb ? vB : bestB; iB = cb ? m : iB;
        }
    }

    // ---- epilogue: gather winners from LDS, smooth-L1 on true coordinates ----
    const float4 tA = sT4[iA];
    const float4 tB = sT4[iB];
    float s = sl1(pAx - tA.x) + sl1(pAy - tA.y) + sl1(pAz - tA.z)
            + sl1(pBx - tB.x) + sl1(pBy - tB.y) + sl1(pBz - tB.z);

    // ---- 7 block reductions batched through one syncthreads ----
    float vals[7] = { s, pAx + pBx, pAy + pBy, pAz + pBz, tsx, tsy, tsz };
    const int lane = tid & 63, wid = tid >> 6;
    #pragma unroll
    for (int k = 0; k < 7; ++k) {
        float v = vals[k];
        #pragma unroll
        for (int off = 32; off; off >>= 1) v += __shfl_down(v, off, 64);
        if (lane == 0) sred[wid][k] = v;
    }
    __syncthreads();
    if (tid == 0) {
        float tot[7];
        #pragma unroll
        for (int k = 0; k < 7; ++k)
            tot[k] = sred[0][k] + sred[1][k] + sred[2][k] + sred[3][k];
        ws[WS_PARTIAL + blockIdx.x] = tot[0] * W[bt];        // weighted sl1 sum
        ws[WS_PSUM + blockIdx.x * 3 + 0] = tot[1];
        ws[WS_PSUM + blockIdx.x * 3 + 1] = tot[2];
        ws[WS_PSUM + blockIdx.x * 3 + 2] = tot[3];
        if (ph == 0) {
            ws[WS_TSUM + bt * 3 + 0] = tot[4];
            ws[WS_TSUM + bt * 3 + 1] = tot[5];
            ws[WS_TSUM + bt * 3 + 2] = tot[6];
        }
    }
}

// One block: sum 224 weighted partials -> out[0]; centroid loss -> out[1].
__global__ __launch_bounds__(256) void finalize_kernel(
    const float* __restrict__ ws, float* __restrict__ out)
{
    __shared__ float sred[4][2];
    const int tid = threadIdx.x;

    float lp = (tid < 224) ? ws[WS_PARTIAL + tid] : 0.0f;

    float lc = 0.0f;
    if (tid < BT) {
        const float inv = 1.0f / Nc;
        #pragma unroll
        for (int c = 0; c < 3; ++c) {
            float pm = (ws[WS_PSUM + (2 * tid) * 3 + c] + ws[WS_PSUM + (2 * tid + 1) * 3 + c]) * inv;
            float tm = ws[WS_TSUM + tid * 3 + c] * inv;
            lc += sl1(pm - tm);
        }
    }

    const int lane = tid & 63, wid = tid >> 6;
    #pragma unroll
    for (int off = 32; off; off >>= 1) {
        lp += __shfl_down(lp, off, 64);
        lc += __shfl_down(lc, off, 64);
    }
    if (lane == 0) { sred[wid][0] = lp; sred[wid][1] = lc; }
    __syncthreads();
    if (tid == 0) {
        float tlp = sred[0][0] + sred[1][0] + sred[2][0] + sred[3][0];
        float tlc = sred[0][1] + sred[1][1] + sred[2][1] + sred[3][1];
        out[0] = tlp * (1.0f / (Nc * Dc)) * (1.0f / Bc);  // loss
        out[1] = tlc * (1.0f / (Bc * Dc));                // lossc
    }
}

extern "C" void kernel_launch(void* const* d_in, const int* in_sizes, int n_in,
                              void* d_out, int out_size, void* d_ws, size_t ws_size,
                              hipStream_t stream) {
    const float* X  = (const float*)d_in[0];  // X_v        [4,28,1024,3]
    const float* Tg = (const float*)d_in[1];  // target_X_v [4,28,1024,3]
    const float* W  = (const float*)d_in[2];  // weights    [4,28]
    float* out = (float*)d_out;               // {loss, lossc}
    float* ws  = (float*)d_ws;                // 1232 floats, all written before read

    chamfer_kernel<<<BT * 2, 256, 0, stream>>>(X, Tg, W, ws);
    finalize_kernel<<<1, 256, 0, stream>>>(ws, out);
}